// Round 11
// baseline (159.859 us; speedup 1.0000x reference)
//
#include <hip/hip_runtime.h>
#include <stdint.h>

typedef unsigned short u16;
typedef short bf16x8 __attribute__((ext_vector_type(8)));
typedef float f32x4 __attribute__((ext_vector_type(4)));

#define S_ 2048
#define HID_ 1024
#define H_ 16
#define D_ 64

#define LOG2E 1.4426950408889634f
#define SCALE_LOG2 0.18033688011112042f   /* 0.125 * log2(e) */
#define MAXC_LOG2 11.541560327111707f     /* 8 * log2(e) */

__device__ __forceinline__ u16 f2bf(float f) {
  uint32_t x = __builtin_bit_cast(uint32_t, f);
  uint32_t r = (x + 0x7fffu + ((x >> 16) & 1u)) >> 16;
  return (u16)r;
}
__device__ __forceinline__ uint32_t packbf2(float a, float b) {
  return (uint32_t)f2bf(a) | ((uint32_t)f2bf(b) << 16);
}
// truncating pack: low16 = bf16(a), high16 = bf16(b), one v_perm_b32
__device__ __forceinline__ uint32_t permpack(float a, float b) {
  return __builtin_amdgcn_perm(__builtin_bit_cast(uint32_t, b),
                               __builtin_bit_cast(uint32_t, a), 0x07060302u);
}

__device__ __forceinline__ void gl2lds16(const void* g, void* l) {
  __builtin_amdgcn_global_load_lds(
      (const __attribute__((address_space(1))) unsigned int*)g,
      (__attribute__((address_space(3))) unsigned int*)l, 16, 0, 0);
}

// ------------- prep: converts + RoPE tables + mask2, one kernel -------------
#define NX_ (1 << 20)
#define NW_ (1 << 18)
#define NROPE_ 65536
__global__ void prep_kernel(const float* __restrict__ X, const float* __restrict__ Wq,
                            const float* __restrict__ Wk, const float* __restrict__ Wv,
                            const float* __restrict__ mask, u16* __restrict__ Xb,
                            u16* __restrict__ Wqb, u16* __restrict__ Wkb,
                            u16* __restrict__ Wvb, float* __restrict__ cos_t,
                            float* __restrict__ sin_t, float* __restrict__ mask2) {
  int i = blockIdx.x * 256 + threadIdx.x;
  if (i < NX_ + 3 * NW_) {
    const float* src;
    u16* dst;
    int off;
    if (i < NX_) {
      src = X; dst = Xb; off = i;
    } else if (i < NX_ + NW_) {
      src = Wq; dst = Wqb; off = i - NX_;
    } else if (i < NX_ + 2 * NW_) {
      src = Wk; dst = Wkb; off = i - NX_ - NW_;
    } else {
      src = Wv; dst = Wvb; off = i - NX_ - 2 * NW_;
    }
    float4 v = ((const float4*)src)[off];
    uint2 packed;
    packed.x = packbf2(v.x, v.y);
    packed.y = packbf2(v.z, v.w);
    ((uint2*)dst)[off] = packed;
  } else if (i < NX_ + 3 * NW_ + NROPE_) {
    int t = i - (NX_ + 3 * NW_);  // 65536 = 2048*32
    int s = t >> 5, j = t & 31;
    float invf = powf(10000.0f, -(float)j * (1.0f / 32.0f));
    float ang = (float)s * invf;
    cos_t[t] = cosf(ang);
    sin_t[t] = sinf(ang);
  } else {
    int t = i - (NX_ + 3 * NW_ + NROPE_);  // 4096 = 2*2048
    mask2[t] = fmaf(mask[t], LOG2E, -MAXC_LOG2);
  }
}

// ---------------- Fused QKV GEMM: 3-phase/K-tile schedule, counted vmcnt (T3+T4+T5) ----------------
// grid (8, 32) = 256 blocks = 1/CU. 512 threads (8 waves 2m x 4n). LDS 128 KB dbuf:
// buf p @ p*65536 { A @+0, Bq @+16K, Bk @+32K, Bv @+48K }. Staging split into halves
// H0 = A+Bq (4 gl2lds/thread), H1 = Bk+Bv, staggered: H0(kk+1) issued in phase 0 of kk,
// H1(kk+1) in phase 1. Per K-tile, 3 phases of 16 MFMA (Q, K, V clusters; afrag read
// once in phase 0, held in regs). Each phase: {ds_reads; stage; [vmcnt]; barrier;
// lgkmcnt(0); sched_barrier; setprio(1); 16 MFMA; setprio(0); barrier} (m201 skeleton).
// Wait ledger (invariant: outstanding at tile entry = H1(kk) only):
//   end of phase 0: vmcnt(4) retires H1(kk)   (H0(kk+1) stays in flight)
//   end of phase 2: vmcnt(4) retires H0(kk+1) (H1(kk+1) stays in flight)
// -> counted vmcnt never 0 in steady state; loads get >=2 phases of MFMA cover.
// Rationale: 2-phase structure was <10% MFMA-util (6300 cy/K-step vs 480 cy MFMA);
// R8 showed T4-without-T3 is null (matches m230); this is the T3+T4 combo.
__global__ __launch_bounds__(512, 2) void qkv_gemm_kernel(
    const u16* __restrict__ X, const u16* __restrict__ Wq, const u16* __restrict__ Wk,
    const u16* __restrict__ Wv, const float* __restrict__ cos_t,
    const float* __restrict__ sin_t, u16* __restrict__ Q, u16* __restrict__ K,
    u16* __restrict__ Vt) {
  __shared__ char smem[131072];
  int tid = threadIdx.x;
  int lane = tid & 63, wave = tid >> 6;
  int wm = wave >> 2, wn = wave & 3;
  int quad = lane >> 4, l16 = lane & 15;
  int nbase = blockIdx.x * 128;
  int mbase = blockIdx.y * 128;

  // H0 = A (it 0,1) + Bq (it 2,3); H1 = Bk (it 4,5) + Bv (it 6,7).
#define STAGE_HALF(k0, buf, IT0)                                                  \
  {                                                                               \
    _Pragma("unroll") for (int it = (IT0); it < (IT0) + 4; ++it) {                \
      int j = (it & 1) * 512 + tid;                                               \
      int r = j >> 3, gs = j & 7, gsrc = gs ^ (r & 7);                            \
      const u16* src; int rb;                                                     \
      if ((it >> 1) == 0)      { src = X;  rb = mbase + r; }                      \
      else if ((it >> 1) == 1) { src = Wq; rb = nbase + r; }                      \
      else if ((it >> 1) == 2) { src = Wk; rb = nbase + r; }                      \
      else                     { src = Wv; rb = nbase + r; }                      \
      gl2lds16(src + (size_t)rb * HID_ + (k0) + gsrc * 8,                         \
               (buf) + (it >> 1) * 16384 + j * 16);                               \
    }                                                                             \
  }

  // phase closer: [optional vmcnt] barrier; lgkm(0); sched_barrier
#define PHASE_GATE                                                     \
  __builtin_amdgcn_s_barrier();                                        \
  asm volatile("s_waitcnt lgkmcnt(0)" ::: "memory");                   \
  __builtin_amdgcn_sched_barrier(0);

  // prologue: stage tile 0 fully, drain, join
  STAGE_HALF(0, smem, 0)
  STAGE_HALF(0, smem, 4)
  asm volatile("s_waitcnt vmcnt(0)" ::: "memory");
  __builtin_amdgcn_s_barrier();

  f32x4 acc[3][4][2] = {};  // [which][i4 m-block][j2 n-pair]

  for (int kk = 0; kk < 16; ++kk) {
    const char* buf = smem + (kk & 1) * 65536;
    char* nbuf = smem + ((kk + 1) & 1) * 65536;
    int k0n = (kk + 1) * 64;

    bf16x8 af[2][4], bf[2][2];

    // ======== phase 0: Q ========
#pragma unroll
    for (int kh = 0; kh < 2; ++kh)
#pragma unroll
      for (int i4 = 0; i4 < 4; ++i4) {
        int r = wm * 64 + i4 * 16 + l16;
        int L = r * 8 + ((kh * 4 + quad) ^ (r & 7));
        af[kh][i4] = *(const bf16x8*)(buf + L * 16);
      }
#pragma unroll
    for (int kh = 0; kh < 2; ++kh)
#pragma unroll
      for (int j2 = 0; j2 < 2; ++j2) {
        int r = (wn >> 1) * 64 + (wn & 1) * 16 + j2 * 32 + l16;
        int L = r * 8 + ((kh * 4 + quad) ^ (r & 7));
        bf[kh][j2] = *(const bf16x8*)(buf + 16384 + L * 16);
      }
    if (kk < 15) {
      STAGE_HALF(k0n, nbuf, 0)  // H0(kk+1)
      asm volatile("s_waitcnt vmcnt(4)" ::: "memory");  // retire H1(kk)
    } else {
      asm volatile("s_waitcnt vmcnt(0)" ::: "memory");  // retire H1(15)
    }
    PHASE_GATE
    __builtin_amdgcn_s_setprio(1);
#pragma unroll
    for (int kh = 0; kh < 2; ++kh)
#pragma unroll
      for (int i4 = 0; i4 < 4; ++i4)
#pragma unroll
        for (int j2 = 0; j2 < 2; ++j2)
          acc[0][i4][j2] = __builtin_amdgcn_mfma_f32_16x16x32_bf16(
              bf[kh][j2], af[kh][i4], acc[0][i4][j2], 0, 0, 0);
    __builtin_amdgcn_s_setprio(0);
    __builtin_amdgcn_s_barrier();

    // ======== phase 1: K ========
#pragma unroll
    for (int kh = 0; kh < 2; ++kh)
#pragma unroll
      for (int j2 = 0; j2 < 2; ++j2) {
        int r = (wn >> 1) * 64 + (wn & 1) * 16 + j2 * 32 + l16;
        int L = r * 8 + ((kh * 4 + quad) ^ (r & 7));
        bf[kh][j2] = *(const bf16x8*)(buf + 32768 + L * 16);
      }
    if (kk < 15) STAGE_HALF(k0n, nbuf, 4)  // H1(kk+1); no vmcnt here
    PHASE_GATE
    __builtin_amdgcn_s_setprio(1);
#pragma unroll
    for (int kh = 0; kh < 2; ++kh)
#pragma unroll
      for (int i4 = 0; i4 < 4; ++i4)
#pragma unroll
        for (int j2 = 0; j2 < 2; ++j2)
          acc[1][i4][j2] = __builtin_amdgcn_mfma_f32_16x16x32_bf16(
              bf[kh][j2], af[kh][i4], acc[1][i4][j2], 0, 0, 0);
    __builtin_amdgcn_s_setprio(0);
    __builtin_amdgcn_s_barrier();

    // ======== phase 2: V ========
#pragma unroll
    for (int kh = 0; kh < 2; ++kh)
#pragma unroll
      for (int j2 = 0; j2 < 2; ++j2) {
        int r = (wn >> 1) * 64 + (wn & 1) * 16 + j2 * 32 + l16;
        int L = r * 8 + ((kh * 4 + quad) ^ (r & 7));
        bf[kh][j2] = *(const bf16x8*)(buf + 49152 + L * 16);
      }
    if (kk < 15)
      asm volatile("s_waitcnt vmcnt(4)" ::: "memory");  // retire H0(kk+1)
    PHASE_GATE
    __builtin_amdgcn_s_setprio(1);
#pragma unroll
    for (int kh = 0; kh < 2; ++kh)
#pragma unroll
      for (int i4 = 0; i4 < 4; ++i4)
#pragma unroll
        for (int j2 = 0; j2 < 2; ++j2)
          acc[2][i4][j2] = __builtin_amdgcn_mfma_f32_16x16x32_bf16(
              af[kh][i4], bf[kh][j2], acc[2][i4][j2], 0, 0, 0);
    __builtin_amdgcn_s_setprio(0);
    __builtin_amdgcn_s_barrier();
  }
#undef STAGE_HALF
#undef PHASE_GATE

  // ---- V epilogue (w=2, non-swapped): C row = m (quad*4+reg), col = n (l16) ----
#pragma unroll
  for (int i4 = 0; i4 < 4; ++i4)
#pragma unroll
    for (int j2 = 0; j2 < 2; ++j2) {
      int m = mbase + wm * 64 + i4 * 16 + quad * 4;
      int n = nbase + (wn >> 1) * 64 + (wn & 1) * 16 + j2 * 32 + l16;
      int b = m >> 11, s0 = m & 2047;
      int h = n >> 6, d = n & 63;
      uint2 pk;
      pk.x = packbf2(acc[2][i4][j2][0], acc[2][i4][j2][1]);
      pk.y = packbf2(acc[2][i4][j2][2], acc[2][i4][j2][3]);
      *(uint2*)(Vt + (((size_t)(b * H_ + h)) * D_ + d) * S_ + s0) = pk;
    }

  // ---- Q/K epilogue (swapped): C row = n (quad*4+reg), col = m (l16); fused RoPE ----
#pragma unroll
  for (int w = 0; w < 2; ++w) {
    u16* dst = (w == 0) ? Q : K;
#pragma unroll
    for (int i4 = 0; i4 < 4; ++i4) {
      int m = mbase + wm * 64 + i4 * 16 + l16;
      int n1 = nbase + (wn >> 1) * 64 + (wn & 1) * 16 + quad * 4;
      int b = m >> 11, s = m & 2047;
      int h = n1 >> 6, d1 = n1 & 63;  // d1 in [0,32), multiple of 4
      float4 c4 = *(const float4*)(cos_t + s * 32 + d1);
      float4 s4 = *(const float4*)(sin_t + s * 32 + d1);
      float y1[4], y2[4];
#pragma unroll
      for (int r = 0; r < 4; ++r) {
        float cr = ((const float*)&c4)[r], sr = ((const float*)&s4)[r];
        float x1 = acc[w][i4][0][r], x2 = acc[w][i4][1][r];
        y1[r] = x1 * cr - x2 * sr;
        y2[r] = x2 * cr + x1 * sr;
      }
      size_t base = ((size_t)(b * H_ + h) * S_ + s) * D_;
      uint2 p1, p2;
      p1.x = packbf2(y1[0], y1[1]);
      p1.y = packbf2(y1[2], y1[3]);
      p2.x = packbf2(y2[0], y2[1]);
      p2.y = packbf2(y2[2], y2[3]);
      *(uint2*)(dst + base + d1) = p1;
      *(uint2*)(dst + base + d1 + 32) = p2;
    }
  }
}

// ---------- flash helpers ----------
// fixed-max softmax (exp2 + truncating perm-pack), then IN-REGISTER q<->key
// transpose via permlane swaps (R4 proven, bit-identical P routing).
__device__ __forceinline__ void softmax_pack(const f32x4 (*s)[4], const float4* mv,
                                             bf16x8 (*pp)[2]) {
#pragma unroll
  for (int qb = 0; qb < 2; ++qb) {
    uint32_t a[4][2];
#pragma unroll
    for (int jt = 0; jt < 4; ++jt) {
      float pf[4];
#pragma unroll
      for (int r = 0; r < 4; ++r) {
        float mvr = ((const float*)&mv[jt])[r];
        pf[r] = __builtin_amdgcn_exp2f(fmaf(s[qb][jt][r], SCALE_LOG2, mvr));
      }
      a[jt][0] = permpack(pf[0], pf[1]);
      a[jt][1] = permpack(pf[2], pf[3]);
    }
#pragma unroll
    for (int kh = 0; kh < 2; ++kh) {
      uint32_t tt[4];
#pragma unroll
      for (int i = 0; i < 2; ++i) {
        auto r1 = __builtin_amdgcn_permlane32_swap(a[2 * kh][i], a[2 * kh + 1][i],
                                                   false, false);
        auto r2 = __builtin_amdgcn_permlane16_swap(r1[0], r1[1], false, false);
        tt[i] = r2[0];      // T[kh][0+i]
        tt[2 + i] = r2[1];  // T[kh][2+i]
      }
      union { uint32_t u[4]; bf16x8 v; } cv;
      cv.u[0] = tt[0]; cv.u[1] = tt[1]; cv.u[2] = tt[2]; cv.u[3] = tt[3];
      pp[qb][kh] = cv.v;
    }
  }
}

// ---------------- Flash attention (R10 proven): R6 structure, issue-thinned ----------------
// grid (16, 32), 2 blocks/CU, 4 waves x 32 q, 64-key tiles, K/V triple-buffer
// (48 KB), P in registers, 1 barrier/tile. Static LDS addressing (x3 unroll),
// zero-C QK, pointer-advanced staging/mask.
__global__ __launch_bounds__(256, 2) void flash_kernel(
    const u16* __restrict__ Q, const u16* __restrict__ K, const u16* __restrict__ Vt,
    const float* __restrict__ mask2, float* __restrict__ out) {
  __shared__ char smem[49152];  // slot t%3 @ t*16384: K @ +0, V @ +8192
  int tid = threadIdx.x, wave = tid >> 6;
  int lane = tid & 63;
  int quad = lane >> 4, l16 = lane & 15;
  int bh = blockIdx.y, b = bh >> 4, h = bh & 15;
  int qw = blockIdx.x * 128 + wave * 32;
  const u16* Kbase = K + (size_t)bh * S_ * D_;
  const u16* Vbase = Vt + (size_t)bh * D_ * S_;

  // tile-invariant per-lane LDS read bases (kh = 0 / 1)
  char* bk0 = smem + l16 * 128 + ((quad ^ (l16 & 7)) * 16);
  char* bk1 = smem + l16 * 128 + (((4 + quad) ^ (l16 & 7)) * 16);

  // staging lane offsets (r = tid>>3 plus +32 for second half; r&7 invariant)
  int r0 = tid >> 3, gs = tid & 7, gsrc = gs ^ (r0 & 7);
  size_t koff = (size_t)r0 * D_ + gsrc * 8;
  size_t voff = (size_t)r0 * S_ + gsrc * 8;
  const u16* kg = Kbase;  // advances 64*D_ per staged tile
  const u16* vg = Vbase;  // advances 64 per staged tile
  const float* mq = mask2 + b * S_;  // advances 64 per consumed mask tile

#define STAGE(SB)                                                      \
  {                                                                    \
    gl2lds16(kg + koff, smem + (SB) * 16384 + tid * 16);               \
    gl2lds16(kg + koff + 32 * D_, smem + (SB) * 16384 + 4096 + tid * 16); \
    gl2lds16(vg + voff, smem + (SB) * 16384 + 8192 + tid * 16);        \
    gl2lds16(vg + voff + 32 * S_, smem + (SB) * 16384 + 12288 + tid * 16); \
    kg += 64 * D_;                                                     \
    vg += 64;                                                          \
  }

#define MVLOAD                                                         \
  {                                                                    \
    _Pragma("unroll") for (int jt = 0; jt < 4; ++jt)                   \
        mv[jt] = *(const float4*)(mq + jt * 16 + quad * 4);            \
    mq += 64;                                                          \
  }

  // QK with zero-C first step: s = kf0*qf0 + 0; s += kf1*qf1
#define QK_Z(KOFF, s)                                                             \
  {                                                                               \
    _Pragma("unroll") for (int jt = 0; jt < 4; ++jt) {                            \
      bf16x8 kf0 = *(const bf16x8*)(bk0 + (KOFF) + jt * 2048);                    \
      bf16x8 kf1 = *(const bf16x8*)(bk1 + (KOFF) + jt * 2048);                    \
      s[0][jt] = __builtin_amdgcn_mfma_f32_16x16x32_bf16(kf0, qfrag[0][0], zc, 0, 0, 0); \
      s[0][jt] = __builtin_amdgcn_mfma_f32_16x16x32_bf16(kf1, qfrag[0][1], s[0][jt], 0, 0, 0); \
      s[1][jt] = __builtin_amdgcn_mfma_f32_16x16x32_bf16(kf0, qfrag[1][0], zc, 0, 0, 0); \
      s[1][jt] = __builtin_amdgcn_mfma_f32_16x16x32_bf16(kf1, qfrag[1][1], s[1][jt], 0, 0, 0); \
    }                                                                             \
  }

#define PV(VOFF)                                                                  \
  {                                                                               \
    lacc[0] = __builtin_amdgcn_mfma_f32_16x16x32_bf16(pp[0][0], ones, lacc[0], 0, 0, 0); \
    lacc[0] = __builtin_amdgcn_mfma_f32_16x16x32_bf16(pp[0][1], ones, lacc[0], 0, 0, 0); \
    lacc[1] = __builtin_amdgcn_mfma_f32_16x16x32_bf16(pp[1][0], ones, lacc[1], 0, 0, 0); \
    lacc[1] = __builtin_amdgcn_mfma_f32_16x16x32_bf16(pp[1][1], ones, lacc[1], 0, 0, 0); \
    _Pragma("unroll") for (int jd = 0; jd < 4; ++jd) {                            \
      bf16x8 vf0 = *(const bf16x8*)(bk0 + (VOFF) + jd * 2048);                    \
      bf16x8 vf1 = *(const bf16x8*)(bk1 + (VOFF) + jd * 2048);                    \
      o[0][jd] = __builtin_amdgcn_mfma_f32_16x16x32_bf16(pp[0][0], vf0, o[0][jd], 0, 0, 0); \
      o[0][jd] = __builtin_amdgcn_mfma_f32_16x16x32_bf16(pp[0][1], vf1, o[0][jd], 0, 0, 0); \
      o[1][jd] = __builtin_amdgcn_mfma_f32_16x16x32_bf16(pp[1][0], vf0, o[1][jd], 0, 0, 0); \
      o[1][jd] = __builtin_amdgcn_mfma_f32_16x16x32_bf16(pp[1][1], vf1, o[1][jd], 0, 0, 0); \
    }                                                                             \
  }

#define BODY(M)                                                        \
  {                                                                    \
    __syncthreads();                                                   \
    STAGE(((M) + 1) % 3)                                               \
    __builtin_amdgcn_s_setprio(1);                                     \
    PV((((M) + 2) % 3) * 16384 + 8192)                                 \
    f32x4 s[2][4];                                                     \
    QK_Z((M) * 16384, s)                                               \
    __builtin_amdgcn_s_setprio(0);                                     \
    softmax_pack(s, mv, pp);                                           \
    MVLOAD                                                             \
  }

  bf16x8 qfrag[2][2];
#pragma unroll
  for (int qb = 0; qb < 2; ++qb) {
    const u16* qp = Q + ((size_t)bh * S_ + qw + qb * 16 + l16) * D_ + quad * 8;
    qfrag[qb][0] = *(const bf16x8*)qp;
    qfrag[qb][1] = *(const bf16x8*)(qp + 32);
  }
  bf16x8 ones;
#pragma unroll
  for (int j = 0; j < 8; ++j) ones[j] = (short)0x3f80;  // bf16 1.0
  const f32x4 zc = {0.f, 0.f, 0.f, 0.f};

  f32x4 o[2][4] = {};
  f32x4 lacc[2] = {};
  bf16x8 pp[2][2];  // P(kt) fragments, consumed by PV in iter kt+1
  float4 mv[4];

  // prologue: stage tile 0 (kg/vg advance to tile 1); mv <- tile 0 (mq -> tile 1)
  STAGE(0)
  MVLOAD

  // ---- kt = 0 (peeled: no PV) ----
  {
    __syncthreads();  // tile 0 staged
    STAGE(1)          // tile 1
    f32x4 s[2][4];
    __builtin_amdgcn_s_setprio(1);
    QK_Z(0, s)
    __builtin_amdgcn_s_setprio(0);
    softmax_pack(s, mv, pp);  // pp(0)
    MVLOAD                     // mv <- tile 1
  }

  // ---- steady: kt = 1..30 = 10 x {1,2,0} (M = kt%3 compile-time) ----
  for (int j = 0; j < 10; ++j) {
    BODY(1)
    BODY(2)
    BODY(0)
  }

  // ---- kt = 31 (peeled: no stage, no mask advance; M = 31%3 = 1) ----
  {
    __syncthreads();
    __builtin_amdgcn_s_setprio(1);
    PV(0 * 16384 + 8192)  // PV(30), V slot 30%3 = 0
    f32x4 s[2][4];
    QK_Z(1 * 16384, s)    // K(31) in slot 1
    __builtin_amdgcn_s_setprio(0);
    softmax_pack(s, mv, pp);  // pp(31); mv holds mask tile 31
  }

  // drain: PV(31), V slot 31%3 = 1
  PV(1 * 16384 + 8192)

#undef STAGE
#undef MVLOAD
#undef QK_Z
#undef PV
#undef BODY

  // epilogue: lacc[qb][r] holds the full row-sum for q = qw + qb*16 + quad*4 + r
  float inv[2][4];
#pragma unroll
  for (int qb = 0; qb < 2; ++qb)
#pragma unroll
    for (int r = 0; r < 4; ++r) inv[qb][r] = 1.0f / lacc[qb][r];
#pragma unroll
  for (int qb = 0; qb < 2; ++qb)
#pragma unroll
    for (int jd = 0; jd < 4; ++jd) {
#pragma unroll
      for (int r = 0; r < 4; ++r) {
        int d = jd * 16 + l16;
        int q = qw + qb * 16 + quad * 4 + r;
        out[(((size_t)b * S_ + q) * H_ + h) * D_ + d] = o[qb][jd][r] * inv[qb][r];
      }
    }
}

extern "C" void kernel_launch(void* const* d_in, const int* in_sizes, int n_in,
                              void* d_out, int out_size, void* d_ws, size_t ws_size,
                              hipStream_t stream) {
  const float* hid = (const float*)d_in[0];
  const float* mask = (const float*)d_in[1];
  const float* Wq = (const float*)d_in[2];
  const float* Wk = (const float*)d_in[3];
  const float* Wv = (const float*)d_in[4];
  float* out = (float*)d_out;
  char* ws = (char*)d_ws;

  u16* Xbf = (u16*)ws;                              // 8 MB
  u16* Wqb = (u16*)(ws + (8u << 20));               // 2 MB
  u16* Wkb = (u16*)(ws + (10u << 20));              // 2 MB
  u16* Wvb = (u16*)(ws + (12u << 20));              // 2 MB
  u16* Qb = (u16*)(ws + (14u << 20));               // 8 MB (BH,S,D)
  u16* Kb = (u16*)(ws + (22u << 20));               // 8 MB (BH,S,D)
  u16* Vtb = (u16*)(ws + (30u << 20));              // 8 MB (BH,D,S)
  float* cos_t = (float*)(ws + (38u << 20));        // 256 KB
  float* sin_t = (float*)(ws + (38u << 20) + (256u << 10));
  float* mask2 = (float*)(ws + (38u << 20) + (512u << 10));  // 16 KB

  prep_kernel<<<7440, 256, 0, stream>>>(hid, Wq, Wk, Wv, mask, Xbf, Wqb, Wkb, Wvb,
                                        cos_t, sin_t, mask2);
  qkv_gemm_kernel<<<dim3(8, 32), 512, 0, stream>>>(Xbf, Wqb, Wkb, Wvb, cos_t, sin_t,
                                                   Qb, Kb, Vtb);
  flash_kernel<<<dim3(16, 32), 256, 0, stream>>>(Qb, Kb, Vtb, mask2, out);
}

// Round 12
// 158.181 us; speedup vs baseline: 1.0106x; 1.0106x over previous
//
#include <hip/hip_runtime.h>
#include <stdint.h>

typedef unsigned short u16;
typedef short bf16x8 __attribute__((ext_vector_type(8)));
typedef float f32x4 __attribute__((ext_vector_type(4)));

#define S_ 2048
#define HID_ 1024
#define H_ 16
#define D_ 64

#define LOG2E 1.4426950408889634f
#define SCALE_LOG2 0.18033688011112042f   /* 0.125 * log2(e) */
#define MAXC_LOG2 11.541560327111707f     /* 8 * log2(e) */

__device__ __forceinline__ u16 f2bf(float f) {
  uint32_t x = __builtin_bit_cast(uint32_t, f);
  uint32_t r = (x + 0x7fffu + ((x >> 16) & 1u)) >> 16;
  return (u16)r;
}
__device__ __forceinline__ uint32_t packbf2(float a, float b) {
  return (uint32_t)f2bf(a) | ((uint32_t)f2bf(b) << 16);
}
// truncating pack: low16 = bf16(a), high16 = bf16(b), one v_perm_b32
__device__ __forceinline__ uint32_t permpack(float a, float b) {
  return __builtin_amdgcn_perm(__builtin_bit_cast(uint32_t, b),
                               __builtin_bit_cast(uint32_t, a), 0x07060302u);
}

__device__ __forceinline__ void gl2lds16(const void* g, void* l) {
  __builtin_amdgcn_global_load_lds(
      (const __attribute__((address_space(1))) unsigned int*)g,
      (__attribute__((address_space(3))) unsigned int*)l, 16, 0, 0);
}

// ------------- prep: converts + RoPE tables + mask2, one kernel -------------
#define NX_ (1 << 20)
#define NW_ (1 << 18)
#define NROPE_ 65536
__global__ void prep_kernel(const float* __restrict__ X, const float* __restrict__ Wq,
                            const float* __restrict__ Wk, const float* __restrict__ Wv,
                            const float* __restrict__ mask, u16* __restrict__ Xb,
                            u16* __restrict__ Wqb, u16* __restrict__ Wkb,
                            u16* __restrict__ Wvb, float* __restrict__ cos_t,
                            float* __restrict__ sin_t, float* __restrict__ mask2) {
  int i = blockIdx.x * 256 + threadIdx.x;
  if (i < NX_ + 3 * NW_) {
    const float* src;
    u16* dst;
    int off;
    if (i < NX_) {
      src = X; dst = Xb; off = i;
    } else if (i < NX_ + NW_) {
      src = Wq; dst = Wqb; off = i - NX_;
    } else if (i < NX_ + 2 * NW_) {
      src = Wk; dst = Wkb; off = i - NX_ - NW_;
    } else {
      src = Wv; dst = Wvb; off = i - NX_ - 2 * NW_;
    }
    float4 v = ((const float4*)src)[off];
    uint2 packed;
    packed.x = packbf2(v.x, v.y);
    packed.y = packbf2(v.z, v.w);
    ((uint2*)dst)[off] = packed;
  } else if (i < NX_ + 3 * NW_ + NROPE_) {
    int t = i - (NX_ + 3 * NW_);  // 65536 = 2048*32
    int s = t >> 5, j = t & 31;
    float invf = powf(10000.0f, -(float)j * (1.0f / 32.0f));
    float ang = (float)s * invf;
    cos_t[t] = cosf(ang);
    sin_t[t] = sinf(ang);
  } else {
    int t = i - (NX_ + 3 * NW_ + NROPE_);  // 4096 = 2*2048
    mask2[t] = fmaf(mask[t], LOG2E, -MAXC_LOG2);
  }
}

// ---------------- Fused QKV GEMM (R6 proven, reverted): one block, Q+K+V ----------------
// grid (8, 32) = 256 blocks = 1/CU, zero dispatch tail. 512 threads (8 waves 2m x 4n).
// A staged ONCE per K-step, shared by all 3 B matrices. LDS 128 KB dbuf,
// stage-before-compute, 1 barrier/K-step.
__global__ __launch_bounds__(512, 2) void qkv_gemm_kernel(
    const u16* __restrict__ X, const u16* __restrict__ Wq, const u16* __restrict__ Wk,
    const u16* __restrict__ Wv, const float* __restrict__ cos_t,
    const float* __restrict__ sin_t, u16* __restrict__ Q, u16* __restrict__ K,
    u16* __restrict__ Vt) {
  __shared__ char smem[131072];
  int tid = threadIdx.x;
  int lane = tid & 63, wave = tid >> 6;
  int wm = wave >> 2, wn = wave & 3;
  int quad = lane >> 4, l16 = lane & 15;
  int nbase = blockIdx.x * 128;
  int mbase = blockIdx.y * 128;

#define STAGE_ALL(k0, buf)                                                        \
  {                                                                               \
    _Pragma("unroll") for (int it = 0; it < 8; ++it) {                            \
      int j = (it & 1) * 512 + tid;                                               \
      int r = j >> 3, gs = j & 7, gsrc = gs ^ (r & 7);                            \
      const u16* src; int rb;                                                     \
      if ((it >> 1) == 0)      { src = X;  rb = mbase + r; }                      \
      else if ((it >> 1) == 1) { src = Wq; rb = nbase + r; }                      \
      else if ((it >> 1) == 2) { src = Wk; rb = nbase + r; }                      \
      else                     { src = Wv; rb = nbase + r; }                      \
      gl2lds16(src + (size_t)rb * HID_ + (k0) + gsrc * 8,                         \
               (buf) + (it >> 1) * 16384 + j * 16);                               \
    }                                                                             \
  }

  STAGE_ALL(0, smem)  // tile 0 -> buf 0

  f32x4 acc[3][4][2] = {};  // [which][i4 m-block][j2 n-pair]

  for (int kk = 0; kk < 16; ++kk) {
    const char* buf = smem + (kk & 1) * 65536;
    __syncthreads();  // staging of tile kk complete

    if (kk < 15)  // stage tile kk+1 into other buffer (its reads finished pre-barrier)
      STAGE_ALL((kk + 1) * 64, smem + ((kk + 1) & 1) * 65536)

#pragma unroll
    for (int kh = 0; kh < 2; ++kh) {
      bf16x8 afrag[4];
#pragma unroll
      for (int i4 = 0; i4 < 4; ++i4) {
        int r = wm * 64 + i4 * 16 + l16;
        int L = r * 8 + ((kh * 4 + quad) ^ (r & 7));
        afrag[i4] = *(const bf16x8*)(buf + L * 16);
      }
#pragma unroll
      for (int w = 0; w < 3; ++w) {
        const char* Bs = buf + 16384 + w * 16384;
        bf16x8 bfrag[2];
#pragma unroll
        for (int j2 = 0; j2 < 2; ++j2) {
          int r = (wn >> 1) * 64 + (wn & 1) * 16 + j2 * 32 + l16;
          int L = r * 8 + ((kh * 4 + quad) ^ (r & 7));
          bfrag[j2] = *(const bf16x8*)(Bs + L * 16);
        }
        if (w == 2) {
#pragma unroll
          for (int i4 = 0; i4 < 4; ++i4)
#pragma unroll
            for (int j2 = 0; j2 < 2; ++j2)
              acc[2][i4][j2] = __builtin_amdgcn_mfma_f32_16x16x32_bf16(
                  afrag[i4], bfrag[j2], acc[2][i4][j2], 0, 0, 0);
        } else if (w == 1) {
#pragma unroll
          for (int i4 = 0; i4 < 4; ++i4)
#pragma unroll
            for (int j2 = 0; j2 < 2; ++j2)
              acc[1][i4][j2] = __builtin_amdgcn_mfma_f32_16x16x32_bf16(
                  bfrag[j2], afrag[i4], acc[1][i4][j2], 0, 0, 0);
        } else {
#pragma unroll
          for (int i4 = 0; i4 < 4; ++i4)
#pragma unroll
            for (int j2 = 0; j2 < 2; ++j2)
              acc[0][i4][j2] = __builtin_amdgcn_mfma_f32_16x16x32_bf16(
                  bfrag[j2], afrag[i4], acc[0][i4][j2], 0, 0, 0);
        }
      }
    }
  }
#undef STAGE_ALL

  // ---- V epilogue (w=2, non-swapped): C row = m (quad*4+reg), col = n (l16) ----
#pragma unroll
  for (int i4 = 0; i4 < 4; ++i4)
#pragma unroll
    for (int j2 = 0; j2 < 2; ++j2) {
      int m = mbase + wm * 64 + i4 * 16 + quad * 4;
      int n = nbase + (wn >> 1) * 64 + (wn & 1) * 16 + j2 * 32 + l16;
      int b = m >> 11, s0 = m & 2047;
      int h = n >> 6, d = n & 63;
      uint2 pk;
      pk.x = packbf2(acc[2][i4][j2][0], acc[2][i4][j2][1]);
      pk.y = packbf2(acc[2][i4][j2][2], acc[2][i4][j2][3]);
      *(uint2*)(Vt + (((size_t)(b * H_ + h)) * D_ + d) * S_ + s0) = pk;
    }

  // ---- Q/K epilogue (swapped): C row = n (quad*4+reg), col = m (l16); fused RoPE ----
#pragma unroll
  for (int w = 0; w < 2; ++w) {
    u16* dst = (w == 0) ? Q : K;
#pragma unroll
    for (int i4 = 0; i4 < 4; ++i4) {
      int m = mbase + wm * 64 + i4 * 16 + l16;
      int n1 = nbase + (wn >> 1) * 64 + (wn & 1) * 16 + quad * 4;
      int b = m >> 11, s = m & 2047;
      int h = n1 >> 6, d1 = n1 & 63;  // d1 in [0,32), multiple of 4
      float4 c4 = *(const float4*)(cos_t + s * 32 + d1);
      float4 s4 = *(const float4*)(sin_t + s * 32 + d1);
      float y1[4], y2[4];
#pragma unroll
      for (int r = 0; r < 4; ++r) {
        float cr = ((const float*)&c4)[r], sr = ((const float*)&s4)[r];
        float x1 = acc[w][i4][0][r], x2 = acc[w][i4][1][r];
        y1[r] = x1 * cr - x2 * sr;
        y2[r] = x2 * cr + x1 * sr;
      }
      size_t base = ((size_t)(b * H_ + h) * S_ + s) * D_;
      uint2 p1, p2;
      p1.x = packbf2(y1[0], y1[1]);
      p1.y = packbf2(y1[2], y1[3]);
      p2.x = packbf2(y2[0], y2[1]);
      p2.y = packbf2(y2[2], y2[3]);
      *(uint2*)(dst + base + d1) = p1;
      *(uint2*)(dst + base + d1 + 32) = p2;
    }
  }
}

// ---------- flash helpers ----------
// fixed-max softmax (exp2 + truncating perm-pack), then IN-REGISTER q<->key
// transpose via permlane swaps (R4 proven, bit-identical P routing).
__device__ __forceinline__ void softmax_pack(const f32x4 (*s)[4], const float4* mv,
                                             bf16x8 (*pp)[2]) {
#pragma unroll
  for (int qb = 0; qb < 2; ++qb) {
    uint32_t a[4][2];
#pragma unroll
    for (int jt = 0; jt < 4; ++jt) {
      float pf[4];
#pragma unroll
      for (int r = 0; r < 4; ++r) {
        float mvr = ((const float*)&mv[jt])[r];
        pf[r] = __builtin_amdgcn_exp2f(fmaf(s[qb][jt][r], SCALE_LOG2, mvr));
      }
      a[jt][0] = permpack(pf[0], pf[1]);
      a[jt][1] = permpack(pf[2], pf[3]);
    }
#pragma unroll
    for (int kh = 0; kh < 2; ++kh) {
      uint32_t tt[4];
#pragma unroll
      for (int i = 0; i < 2; ++i) {
        auto r1 = __builtin_amdgcn_permlane32_swap(a[2 * kh][i], a[2 * kh + 1][i],
                                                   false, false);
        auto r2 = __builtin_amdgcn_permlane16_swap(r1[0], r1[1], false, false);
        tt[i] = r2[0];      // T[kh][0+i]
        tt[2 + i] = r2[1];  // T[kh][2+i]
      }
      union { uint32_t u[4]; bf16x8 v; } cv;
      cv.u[0] = tt[0]; cv.u[1] = tt[1]; cv.u[2] = tt[2]; cv.u[3] = tt[3];
      pp[qb][kh] = cv.v;
    }
  }
}

// ---------------- Flash attention: KVBLK=128, same-iter PV, dbuf K/V ----------------
// grid (16, 32), 2 blocks/CU, 4 waves x 32 q. 16 macro-tiles of 128 keys ->
// HALF the barriers (16 vs 32); each period = 2x work (proven 64-key routines
// called twice with shifted bases). Same-iter PV (lag-1 was an LDS-P relic; P
// has been in registers since R4; the serial chain QK->sm->PV is unchanged, only
// a ~50cy trans->MFMA edge is exposed vs a 7700cy period) enables K/V DOUBLE
// buffering: buf p @ p*32768 {K 2x8K @+0, V 2x8K @+16384} = 64 KB. Sub-tile
// interleave QK0->sm0->QK1->sm1->PV lets sm0 VALU overlap QK1 MFMA. Static
// addressing via 2-unrolled parity. Stage(T+1) writes parity T^1, all reads
// parity T (disjoint); cross-period ordering by the single barrier (vmcnt
// drained there by compiler).
__global__ __launch_bounds__(256, 2) void flash_kernel(
    const u16* __restrict__ Q, const u16* __restrict__ K, const u16* __restrict__ Vt,
    const float* __restrict__ mask2, float* __restrict__ out) {
  __shared__ char smem[65536];
  int tid = threadIdx.x, wave = tid >> 6;
  int lane = tid & 63;
  int quad = lane >> 4, l16 = lane & 15;
  int bh = blockIdx.y, b = bh >> 4, h = bh & 15;
  int qw = blockIdx.x * 128 + wave * 32;
  const u16* Kbase = K + (size_t)bh * S_ * D_;
  const u16* Vbase = Vt + (size_t)bh * D_ * S_;

  // tile-invariant per-lane LDS read bases (kh = 0 / 1)
  char* bk0 = smem + l16 * 128 + ((quad ^ (l16 & 7)) * 16);
  char* bk1 = smem + l16 * 128 + (((4 + quad) ^ (l16 & 7)) * 16);

  // staging lane offsets
  int r0 = tid >> 3, gs = tid & 7, gsrc = gs ^ (r0 & 7);
  size_t koff = (size_t)r0 * D_ + gsrc * 8;
  size_t voff = (size_t)r0 * S_ + gsrc * 8;
  const u16* kg = Kbase;             // advances 64*D_ per 64-key sub-stage
  const u16* vg = Vbase;             // advances 64 per 64-key sub-stage
  const float* mq = mask2 + b * S_;  // advances 128 per consumed macro-tile

  // one 64-key sub-tile: K rows -> KD (2x4KB), V d-rows -> VD (2x4KB)
#define STAGE64(KD, VD)                                                \
  {                                                                    \
    gl2lds16(kg + koff, (KD) + tid * 16);                              \
    gl2lds16(kg + koff + 32 * D_, (KD) + 4096 + tid * 16);             \
    gl2lds16(vg + voff, (VD) + tid * 16);                              \
    gl2lds16(vg + voff + 32 * S_, (VD) + 4096 + tid * 16);             \
    kg += 64 * D_;                                                     \
    vg += 64;                                                          \
  }

  // 128-key macro-tile into parity P: K subs @ +0/+8192, V subs @ +16384/+24576
#define STAGE128(P)                                                    \
  {                                                                    \
    STAGE64(smem + (P) * 32768, smem + (P) * 32768 + 16384)            \
    STAGE64(smem + (P) * 32768 + 8192, smem + (P) * 32768 + 24576)     \
  }

#define MVLOAD                                                         \
  {                                                                    \
    _Pragma("unroll") for (int jt = 0; jt < 4; ++jt) {                 \
      mvA[jt] = *(const float4*)(mq + jt * 16 + quad * 4);             \
      mvB[jt] = *(const float4*)(mq + 64 + jt * 16 + quad * 4);        \
    }                                                                  \
    mq += 128;                                                         \
  }

  // QK on sub-tile ST of parity P (zero-C first step), into SA[2][4]
#define QKSUB(P, ST, SA)                                                          \
  {                                                                               \
    _Pragma("unroll") for (int jt = 0; jt < 4; ++jt) {                            \
      bf16x8 kf0 = *(const bf16x8*)(bk0 + (P) * 32768 + (ST) * 8192 + jt * 2048); \
      bf16x8 kf1 = *(const bf16x8*)(bk1 + (P) * 32768 + (ST) * 8192 + jt * 2048); \
      SA[0][jt] = __builtin_amdgcn_mfma_f32_16x16x32_bf16(kf0, qfrag[0][0], zc, 0, 0, 0); \
      SA[0][jt] = __builtin_amdgcn_mfma_f32_16x16x32_bf16(kf1, qfrag[0][1], SA[0][jt], 0, 0, 0); \
      SA[1][jt] = __builtin_amdgcn_mfma_f32_16x16x32_bf16(kf0, qfrag[1][0], zc, 0, 0, 0); \
      SA[1][jt] = __builtin_amdgcn_mfma_f32_16x16x32_bf16(kf1, qfrag[1][1], SA[1][jt], 0, 0, 0); \
    }                                                                             \
  }

  // PV for the full 128-key macro-tile at parity P (ppA: keys 0-63, ppB: 64-127)
#define PV128(P)                                                                  \
  {                                                                               \
    lacc[0] = __builtin_amdgcn_mfma_f32_16x16x32_bf16(ppA[0][0], ones, lacc[0], 0, 0, 0); \
    lacc[0] = __builtin_amdgcn_mfma_f32_16x16x32_bf16(ppA[0][1], ones, lacc[0], 0, 0, 0); \
    lacc[0] = __builtin_amdgcn_mfma_f32_16x16x32_bf16(ppB[0][0], ones, lacc[0], 0, 0, 0); \
    lacc[0] = __builtin_amdgcn_mfma_f32_16x16x32_bf16(ppB[0][1], ones, lacc[0], 0, 0, 0); \
    lacc[1] = __builtin_amdgcn_mfma_f32_16x16x32_bf16(ppA[1][0], ones, lacc[1], 0, 0, 0); \
    lacc[1] = __builtin_amdgcn_mfma_f32_16x16x32_bf16(ppA[1][1], ones, lacc[1], 0, 0, 0); \
    lacc[1] = __builtin_amdgcn_mfma_f32_16x16x32_bf16(ppB[1][0], ones, lacc[1], 0, 0, 0); \
    lacc[1] = __builtin_amdgcn_mfma_f32_16x16x32_bf16(ppB[1][1], ones, lacc[1], 0, 0, 0); \
    _Pragma("unroll") for (int jd = 0; jd < 4; ++jd) {                            \
      bf16x8 v00 = *(const bf16x8*)(bk0 + (P) * 32768 + 16384 + jd * 2048);       \
      bf16x8 v01 = *(const bf16x8*)(bk1 + (P) * 32768 + 16384 + jd * 2048);       \
      bf16x8 v10 = *(const bf16x8*)(bk0 + (P) * 32768 + 24576 + jd * 2048);       \
      bf16x8 v11 = *(const bf16x8*)(bk1 + (P) * 32768 + 24576 + jd * 2048);       \
      o[0][jd] = __builtin_amdgcn_mfma_f32_16x16x32_bf16(ppA[0][0], v00, o[0][jd], 0, 0, 0); \
      o[0][jd] = __builtin_amdgcn_mfma_f32_16x16x32_bf16(ppA[0][1], v01, o[0][jd], 0, 0, 0); \
      o[0][jd] = __builtin_amdgcn_mfma_f32_16x16x32_bf16(ppB[0][0], v10, o[0][jd], 0, 0, 0); \
      o[0][jd] = __builtin_amdgcn_mfma_f32_16x16x32_bf16(ppB[0][1], v11, o[0][jd], 0, 0, 0); \
      o[1][jd] = __builtin_amdgcn_mfma_f32_16x16x32_bf16(ppA[1][0], v00, o[1][jd], 0, 0, 0); \
      o[1][jd] = __builtin_amdgcn_mfma_f32_16x16x32_bf16(ppA[1][1], v01, o[1][jd], 0, 0, 0); \
      o[1][jd] = __builtin_amdgcn_mfma_f32_16x16x32_bf16(ppB[1][0], v10, o[1][jd], 0, 0, 0); \
      o[1][jd] = __builtin_amdgcn_mfma_f32_16x16x32_bf16(ppB[1][1], v11, o[1][jd], 0, 0, 0); \
    }                                                                             \
  }

  // full period T at parity P: sync; stage(T+1); QK0;sm0;QK1;sm1; mv(T+1); PV(T)
#define BODY(P)                                                        \
  {                                                                    \
    __syncthreads();                                                   \
    STAGE128((P) ^ 1)                                                  \
    __builtin_amdgcn_s_setprio(1);                                     \
    f32x4 sS0[2][4];                                                   \
    QKSUB(P, 0, sS0)                                                   \
    __builtin_amdgcn_s_setprio(0);                                     \
    softmax_pack(sS0, mvA, ppA);                                       \
    __builtin_amdgcn_s_setprio(1);                                     \
    f32x4 sS1[2][4];                                                   \
    QKSUB(P, 1, sS1)                                                   \
    __builtin_amdgcn_s_setprio(0);                                     \
    softmax_pack(sS1, mvB, ppB);                                       \
    MVLOAD                                                             \
    __builtin_amdgcn_s_setprio(1);                                     \
    PV128(P)                                                           \
    __builtin_amdgcn_s_setprio(0);                                     \
  }

  bf16x8 qfrag[2][2];
#pragma unroll
  for (int qb = 0; qb < 2; ++qb) {
    const u16* qp = Q + ((size_t)bh * S_ + qw + qb * 16 + l16) * D_ + quad * 8;
    qfrag[qb][0] = *(const bf16x8*)qp;
    qfrag[qb][1] = *(const bf16x8*)(qp + 32);
  }
  bf16x8 ones;
#pragma unroll
  for (int j = 0; j < 8; ++j) ones[j] = (short)0x3f80;  // bf16 1.0
  const f32x4 zc = {0.f, 0.f, 0.f, 0.f};

  f32x4 o[2][4] = {};
  f32x4 lacc[2] = {};
  bf16x8 ppA[2][2], ppB[2][2];
  float4 mvA[4], mvB[4];

  // prologue: stage macro-tile 0 into parity 0; mask tile 0
  STAGE128(0)
  MVLOAD

  // T = 0 (parity 0; stages tile 1) then T = 1..14 as 7 parity pairs
  BODY(0)
  for (int j = 0; j < 7; ++j) {
    BODY(1)
    BODY(0)
  }

  // ---- T = 15 (parity 1; no stage, no mask advance) ----
  {
    __syncthreads();
    __builtin_amdgcn_s_setprio(1);
    f32x4 sS0[2][4];
    QKSUB(1, 0, sS0)
    __builtin_amdgcn_s_setprio(0);
    softmax_pack(sS0, mvA, ppA);
    __builtin_amdgcn_s_setprio(1);
    f32x4 sS1[2][4];
    QKSUB(1, 1, sS1)
    __builtin_amdgcn_s_setprio(0);
    softmax_pack(sS1, mvB, ppB);
    __builtin_amdgcn_s_setprio(1);
    PV128(1)
    __builtin_amdgcn_s_setprio(0);
  }

#undef STAGE64
#undef STAGE128
#undef MVLOAD
#undef QKSUB
#undef PV128
#undef BODY

  // epilogue: lacc[qb][r] holds the full row-sum for q = qw + qb*16 + quad*4 + r
  float inv[2][4];
#pragma unroll
  for (int qb = 0; qb < 2; ++qb)
#pragma unroll
    for (int r = 0; r < 4; ++r) inv[qb][r] = 1.0f / lacc[qb][r];
#pragma unroll
  for (int qb = 0; qb < 2; ++qb)
#pragma unroll
    for (int jd = 0; jd < 4; ++jd) {
#pragma unroll
      for (int r = 0; r < 4; ++r) {
        int d = jd * 16 + l16;
        int q = qw + qb * 16 + quad * 4 + r;
        out[(((size_t)b * S_ + q) * H_ + h) * D_ + d] = o[qb][jd][r] * inv[qb][r];
      }
    }
}

extern "C" void kernel_launch(void* const* d_in, const int* in_sizes, int n_in,
                              void* d_out, int out_size, void* d_ws, size_t ws_size,
                              hipStream_t stream) {
  const float* hid = (const float*)d_in[0];
  const float* mask = (const float*)d_in[1];
  const float* Wq = (const float*)d_in[2];
  const float* Wk = (const float*)d_in[3];
  const float* Wv = (const float*)d_in[4];
  float* out = (float*)d_out;
  char* ws = (char*)d_ws;

  u16* Xbf = (u16*)ws;                              // 8 MB
  u16* Wqb = (u16*)(ws + (8u << 20));               // 2 MB
  u16* Wkb = (u16*)(ws + (10u << 20));              // 2 MB
  u16* Wvb = (u16*)(ws + (12u << 20));              // 2 MB
  u16* Qb = (u16*)(ws + (14u << 20));               // 8 MB (BH,S,D)
  u16* Kb = (u16*)(ws + (22u << 20));               // 8 MB (BH,S,D)
  u16* Vtb = (u16*)(ws + (30u << 20));              // 8 MB (BH,D,S)
  float* cos_t = (float*)(ws + (38u << 20));        // 256 KB
  float* sin_t = (float*)(ws + (38u << 20) + (256u << 10));
  float* mask2 = (float*)(ws + (38u << 20) + (512u << 10));  // 16 KB

  prep_kernel<<<7440, 256, 0, stream>>>(hid, Wq, Wk, Wv, mask, Xbf, Wqb, Wkb, Wvb,
                                        cos_t, sin_t, mask2);
  qkv_gemm_kernel<<<dim3(8, 32), 512, 0, stream>>>(Xbf, Wqb, Wkb, Wvb, cos_t, sin_t,
                                                   Qb, Kb, Vtb);
  flash_kernel<<<dim3(16, 32), 256, 0, stream>>>(Qb, Kb, Vtb, mask2, out);
}